// Round 3
// baseline (289.937 us; speedup 1.0000x reference)
//
#include <hip/hip_runtime.h>
#include <hip/hip_bf16.h>

#define BQ 4
#define QN 8192
#define DD 256
#define LL 2
#define H0c 128
#define W0c 128
#define H1c 64
#define W1c 64
#define EPSF 1e-5f

typedef unsigned short ushort_t;
typedef __attribute__((ext_vector_type(8))) short short8;
typedef __attribute__((ext_vector_type(4))) float floatx4;
typedef __attribute__((ext_vector_type(4))) _Float16 half4;

static __device__ __forceinline__ float bf2f(unsigned short u) {
    union { unsigned int u; float f; } x;
    x.u = ((unsigned int)u) << 16;
    return x.f;
}
static __device__ __forceinline__ unsigned short f2bf(float f) {
    __hip_bfloat16 h = __float2bfloat16(f);
    return __builtin_bit_cast(unsigned short, h);
}

// ---------------- Kernel 1: transpose (B,D,H,W) fp32 -> (B,H,W,D) bf16 ----------------
// Also reused for Wout (D=256, HW=256, B=1): WoutT[n][k] = Wout[k][n].
__global__ __launch_bounds__(256) void transpose_cast(const float* __restrict__ in,
                                                      __hip_bfloat16* __restrict__ out,
                                                      int HW) {
    __shared__ float tile[32][33];
    int b   = blockIdx.z;
    int hw0 = blockIdx.x * 32;
    int c0  = blockIdx.y * 32;
    const float* inb = in + (size_t)b * DD * HW;
    __hip_bfloat16* outb = out + (size_t)b * DD * HW;
    int tx = threadIdx.x, ty = threadIdx.y;
#pragma unroll
    for (int j = 0; j < 32; j += 8)
        tile[ty + j][tx] = inb[(size_t)(c0 + ty + j) * HW + hw0 + tx];
    __syncthreads();
#pragma unroll
    for (int j = 0; j < 32; j += 8)
        outb[(size_t)(hw0 + ty + j) * DD + c0 + tx] = __float2bfloat16(tile[tx][ty + j]);
}

// ---------------- Kernel 2: pack [Wrd|Woff|Wattn|0] -> Wall[256][64] fp32, biases -> bias64 ----------------
__global__ __launch_bounds__(256) void pack_wall(const float* __restrict__ Wrd, const float* __restrict__ brd,
                                                 const float* __restrict__ Woff, const float* __restrict__ boff,
                                                 const float* __restrict__ Wattn, const float* __restrict__ battn,
                                                 float* __restrict__ Wall, float* __restrict__ bias64) {
    int idx = blockIdx.x * 256 + threadIdx.x;   // 0..16383
    int k = idx >> 6, c = idx & 63;
    float v = (c < 4)  ? Wrd[k * 4 + c]
            : (c < 36) ? Woff[k * 32 + (c - 4)]
            : (c < 52) ? Wattn[k * 16 + (c - 36)]
            : 0.f;
    Wall[idx] = v;
    if (idx < 64) {
        float bv = (idx < 4)  ? brd[idx]
                 : (idx < 36) ? boff[idx - 4]
                 : (idx < 52) ? battn[idx - 36]
                 : 0.f;
        bias64[idx] = bv;
    }
}

// ---------------- Kernel 3: proj GEMM (fp32) + fused sampling-descriptor epilogue ----------------
// Writes per (query, sample): dsi = int2{corner00 elem offset, (dy<<16)|dx}, dsw = half4{w00,w01,w10,w11}
// where w** are combined attn*bilinear weights and dx/dy are elem deltas to the +x / +y corners.
__global__ __launch_bounds__(256) void proj_desc(const float* __restrict__ q,
                                                 const float* __restrict__ Wall,
                                                 const float* __restrict__ bias64,
                                                 const float* __restrict__ base_ref,
                                                 int2* __restrict__ dsi,
                                                 half4* __restrict__ dsw) {
    __shared__ float As[32][68];
    __shared__ float Bs[32][64];
    __shared__ float prs[64][68];
    int tid = threadIdx.x;
    int tx = tid & 15, ty = tid >> 4;
    int m0 = blockIdx.x * 64;
    float acc[4][4] = {};

    for (int kt = 0; kt < DD; kt += 32) {
#pragma unroll
        for (int j = 0; j < 8; j++) {
            int e = tid + 256 * j;
            int r = e >> 5, k = e & 31;
            As[k][r] = q[(size_t)(m0 + r) * DD + kt + k];
        }
#pragma unroll
        for (int j = 0; j < 8; j++) {
            int e = tid + 256 * j;
            int k = e >> 6, nn = e & 63;
            Bs[k][nn] = Wall[(size_t)(kt + k) * 64 + nn];
        }
        __syncthreads();
#pragma unroll
        for (int k = 0; k < 32; k++) {
            const float4 a4 = *(const float4*)&As[k][ty * 4];
            const float4 b4 = *(const float4*)&Bs[k][tx * 4];
            acc[0][0] += a4.x * b4.x; acc[0][1] += a4.x * b4.y; acc[0][2] += a4.x * b4.z; acc[0][3] += a4.x * b4.w;
            acc[1][0] += a4.y * b4.x; acc[1][1] += a4.y * b4.y; acc[1][2] += a4.y * b4.z; acc[1][3] += a4.y * b4.w;
            acc[2][0] += a4.z * b4.x; acc[2][1] += a4.z * b4.y; acc[2][2] += a4.z * b4.z; acc[2][3] += a4.z * b4.w;
            acc[3][0] += a4.w * b4.x; acc[3][1] += a4.w * b4.y; acc[3][2] += a4.w * b4.z; acc[3][3] += a4.w * b4.w;
        }
        __syncthreads();
    }

    float4 bias = *(const float4*)&bias64[tx * 4];
#pragma unroll
    for (int i = 0; i < 4; i++) {
        float4 v;
        v.x = acc[i][0] + bias.x;
        v.y = acc[i][1] + bias.y;
        v.z = acc[i][2] + bias.z;
        v.w = acc[i][3] + bias.w;
        *(float4*)&prs[ty * 4 + i][tx * 4] = v;
    }
    __syncthreads();

    // descriptor phase: thread = (query 0..63, sample-quad 0..3)
    int ql = tid >> 2, sq = tid & 3;
    int n = m0 + ql, b = n >> 13;        // QN = 8192
    const float* p = prs[ql];

    float mx = p[36];
#pragma unroll
    for (int i = 1; i < 16; i++) mx = fmaxf(mx, p[36 + i]);
    float sum = 0.f;
#pragma unroll
    for (int i = 0; i < 16; i++) sum += __expf(p[36 + i] - mx);
    float inv = 1.f / sum;

#pragma unroll
    for (int u = 0; u < 4; u++) {
        int s = sq * 4 + u;
        int l = s >> 3;
        float a = __expf(p[36 + s] - mx) * inv;

        int W = l ? W1c : W0c;
        int H = l ? H1c : H0c;
        float Wf = (float)W, Hf = (float)H;

        float bx = base_ref[(b * LL + l) * 2 + 0];
        float by = base_ref[(b * LL + l) * 2 + 1];
        bx = fminf(fmaxf(bx, EPSF), 1.f - EPSF);
        by = fminf(fmaxf(by, EPSF), 1.f - EPSF);
        float lgx = logf(bx / (1.f - bx));
        float lgy = logf(by / (1.f - by));
        float refx = 1.f / (1.f + __expf(-(lgx + p[l * 2 + 0])));
        float refy = 1.f / (1.f + __expf(-(lgy + p[l * 2 + 1])));

        float locx = refx + p[4 + s * 2 + 0] / Wf;
        float locy = refy + p[4 + s * 2 + 1] / Hf;
        if (l == 1) locy = locy - floorf(locy);   // jnp.remainder(y, 1.0)

        float gx = locx * 2.f - 1.f;
        float gy = locy * 2.f - 1.f;
        float x = ((gx + 1.f) * Wf - 1.f) * 0.5f;
        float y = ((gy + 1.f) * Hf - 1.f) * 0.5f;
        x = fminf(fmaxf(x, 0.f), Wf - 1.f);
        y = fminf(fmaxf(y, 0.f), Hf - 1.f);
        float x0f = floorf(x), y0f = floorf(y);
        float wx = x - x0f, wy = y - y0f;
        int x0 = (int)x0f, y0 = (int)y0f;
        unsigned int dx = (x0 + 1 <= W - 1) ? DD : 0;            // elems
        unsigned int dy = (y0 + 1 <= H - 1) ? (unsigned)(W * DD) : 0;
        int base = ((b * H + y0) * W + x0) * DD;

        float omx = 1.f - wx, omy = 1.f - wy;
        half4 w;
        w[0] = (_Float16)(a * omx * omy);
        w[1] = (_Float16)(a * wx  * omy);
        w[2] = (_Float16)(a * omx * wy);
        w[3] = (_Float16)(a * wx  * wy);

        dsi[(size_t)n * 16 + s] = make_int2(base, (int)((dy << 16) | dx));
        dsw[(size_t)n * 16 + s] = w;
    }
}

// ---------------- Kernel 4: descriptor-driven sampling -> S bf16 (no LDS, no barriers) ----------------
__global__ __launch_bounds__(256) void sample_kernel(const ushort_t* __restrict__ mapT0,
                                                     const ushort_t* __restrict__ mapT1,
                                                     const int2* __restrict__ dsi,
                                                     const half4* __restrict__ dsw,
                                                     ushort_t* __restrict__ S) {
    int tid = threadIdx.x;
    int qw = __builtin_amdgcn_readfirstlane(tid >> 6);  // wave-uniform local query
    int lx = tid & 63;
    int n = blockIdx.x * 4 + qw;
    int c4 = lx * 4;
    const int2*  gi = dsi + (size_t)n * 16;
    const half4* gw = dsw + (size_t)n * 16;

    float a0 = 0.f, a1 = 0.f, a2 = 0.f, a3 = 0.f;
#pragma unroll
    for (int s = 0; s < 16; s++) {
        int2 g = gi[s];
        half4 wh = gw[s];
        const ushort_t* mp = (s < 8) ? mapT0 : mapT1;
        int dx = g.y & 0xffff;
        int dy = (int)(((unsigned int)g.y) >> 16);
        const ushort_t* p0 = mp + g.x + c4;
        ushort4 u00 = *(const ushort4*)(p0);
        ushort4 u01 = *(const ushort4*)(p0 + dx);
        ushort4 u10 = *(const ushort4*)(p0 + dy);
        ushort4 u11 = *(const ushort4*)(p0 + dx + dy);
        float w00 = (float)wh[0], w01 = (float)wh[1], w10 = (float)wh[2], w11 = (float)wh[3];
        a0 += w00 * bf2f(u00.x) + w01 * bf2f(u01.x) + w10 * bf2f(u10.x) + w11 * bf2f(u11.x);
        a1 += w00 * bf2f(u00.y) + w01 * bf2f(u01.y) + w10 * bf2f(u10.y) + w11 * bf2f(u11.y);
        a2 += w00 * bf2f(u00.z) + w01 * bf2f(u01.z) + w10 * bf2f(u10.z) + w11 * bf2f(u11.z);
        a3 += w00 * bf2f(u00.w) + w01 * bf2f(u01.w) + w10 * bf2f(u10.w) + w11 * bf2f(u11.w);
    }
    ushort4 o;
    o.x = f2bf(a0); o.y = f2bf(a1); o.z = f2bf(a2); o.w = f2bf(a3);
    *(ushort4*)(S + (size_t)n * DD + c4) = o;
}

// ---------------- Kernel 5: out = S(bf16) @ WoutT(bf16)^T + bout via MFMA 16x16x32 ----------------
// A-frag: A[m=lane&15][k=quad*8+j]; B-frag from WoutT[n][k]; C/D: col=lane&15, row=quad*4+reg.
__global__ __launch_bounds__(256) void out_mfma(const ushort_t* __restrict__ S,
                                                const ushort_t* __restrict__ WT,
                                                const float* __restrict__ bout,
                                                float* __restrict__ out) {
    int wave = threadIdx.x >> 6, lane = threadIdx.x & 63;
    int m0 = blockIdx.x * 64 + wave * 16;
    int mrow = lane & 15, quad = lane >> 4;
    const ushort_t* Sp = S + (size_t)(m0 + mrow) * DD + quad * 8;

    floatx4 acc[16];
#pragma unroll
    for (int nt = 0; nt < 16; nt++) acc[nt] = {0.f, 0.f, 0.f, 0.f};

    for (int k0 = 0; k0 < DD; k0 += 32) {
        short8 a = *(const short8*)(Sp + k0);
#pragma unroll
        for (int nt = 0; nt < 16; nt++) {
            short8 b = *(const short8*)(WT + (size_t)(nt * 16 + mrow) * DD + k0 + quad * 8);
            acc[nt] = __builtin_amdgcn_mfma_f32_16x16x32_bf16(a, b, acc[nt], 0, 0, 0);
        }
    }

    int rbase = quad * 4;
#pragma unroll
    for (int nt = 0; nt < 16; nt++) {
        float bv = bout[nt * 16 + mrow];
#pragma unroll
        for (int r = 0; r < 4; r++) {
            out[(size_t)(m0 + rbase + r) * DD + nt * 16 + mrow] = acc[nt][r] + bv;
        }
    }
}

// ---------------- launch ----------------
extern "C" void kernel_launch(void* const* d_in, const int* in_sizes, int n_in,
                              void* d_out, int out_size, void* d_ws, size_t ws_size,
                              hipStream_t stream) {
    const float* q        = (const float*)d_in[0];
    const float* map0     = (const float*)d_in[1];
    const float* map1     = (const float*)d_in[2];
    const float* base_ref = (const float*)d_in[3];
    const float* Wrd      = (const float*)d_in[4];
    const float* brd      = (const float*)d_in[5];
    const float* Woff     = (const float*)d_in[6];
    const float* boff     = (const float*)d_in[7];
    const float* Wattn    = (const float*)d_in[8];
    const float* battn    = (const float*)d_in[9];
    const float* Wout     = (const float*)d_in[10];
    const float* bout     = (const float*)d_in[11];
    float* out = (float*)d_out;

    // workspace layout (bytes) — total 67,305,728 (== round-2 footprint, known to fit)
    char* ws = (char*)d_ws;
    __hip_bfloat16* mapT0  = (__hip_bfloat16*)(ws + 0);          // 33,554,432
    __hip_bfloat16* mapT1  = (__hip_bfloat16*)(ws + 33554432);   //  8,388,608
    __hip_bfloat16* WoutT  = (__hip_bfloat16*)(ws + 41943040);   //    131,072
    float*          Wall   = (float*)(ws + 42074112);            //     65,536
    float*          bias64 = (float*)(ws + 42139648);            //        256
    int2*           dsi    = (int2*)(ws + 42139904);             //  4,194,304 (32768 x 16 x 8B)
    half4*          dsw    = (half4*)(ws + 46334208);            //  4,194,304 (32768 x 16 x 8B)
    ushort_t*       Sbuf   = (ushort_t*)(ws + 50528512);         // 16,777,216 (32768 x 256 bf16)

    // 1. transpose+cast feature maps and Wout
    transpose_cast<<<dim3(H0c * W0c / 32, DD / 32, BQ), dim3(32, 8), 0, stream>>>(map0, mapT0, H0c * W0c);
    transpose_cast<<<dim3(H1c * W1c / 32, DD / 32, BQ), dim3(32, 8), 0, stream>>>(map1, mapT1, H1c * W1c);
    transpose_cast<<<dim3(DD / 32, DD / 32, 1), dim3(32, 8), 0, stream>>>(Wout, WoutT, DD);

    // 2. pack projection weights
    pack_wall<<<dim3(64), dim3(256), 0, stream>>>(Wrd, brd, Woff, boff, Wattn, battn, Wall, bias64);

    // 3. projections (fp32) + sampling descriptors
    proj_desc<<<dim3(BQ * QN / 64), dim3(256), 0, stream>>>(q, Wall, bias64, base_ref, dsi, dsw);

    // 4. sampling (descriptor-driven bf16 gathers)
    sample_kernel<<<dim3(BQ * QN / 4), dim3(256), 0, stream>>>(
        (const ushort_t*)mapT0, (const ushort_t*)mapT1, dsi, dsw, Sbuf);

    // 5. output projection (bf16 MFMA)
    out_mfma<<<dim3(BQ * QN / 64), dim3(256), 0, stream>>>(
        Sbuf, (const ushort_t*)WoutT, bout, out);
}

// Round 4
// 246.329 us; speedup vs baseline: 1.1770x; 1.1770x over previous
//
#include <hip/hip_runtime.h>
#include <hip/hip_bf16.h>

#define BQ 4
#define QN 8192
#define DD 256
#define LL 2
#define H0c 128
#define W0c 128
#define H1c 64
#define W1c 64
#define EPSF 1e-5f

typedef unsigned short ushort_t;
typedef __attribute__((ext_vector_type(8))) short short8;
typedef __attribute__((ext_vector_type(8))) unsigned short ushortx8;
typedef __attribute__((ext_vector_type(4))) float floatx4;
typedef __attribute__((ext_vector_type(4))) _Float16 half4;

static __device__ __forceinline__ float lo16f(unsigned int d) {
    union { unsigned int u; float f; } x; x.u = d << 16; return x.f;
}
static __device__ __forceinline__ float hi16f(unsigned int d) {
    union { unsigned int u; float f; } x; x.u = d & 0xFFFF0000u; return x.f;
}
static __device__ __forceinline__ unsigned short f2bf(float f) {
    __hip_bfloat16 h = __float2bfloat16(f);
    return __builtin_bit_cast(unsigned short, h);
}

// ---------------- Kernel 1: prep — all transposes + weight pack, one launch ----------------
// block ranges: [0,16384) map0-T, [16384,20480) map1-T, [20480,20544) Wout-T, [20544,20608) pack
#define T0B 16384
#define T1B 4096
#define TWB 64
__global__ __launch_bounds__(256) void prep(const float* __restrict__ map0, const float* __restrict__ map1,
                                            const float* __restrict__ Wout,
                                            const float* __restrict__ Wrd, const float* __restrict__ brd,
                                            const float* __restrict__ Woff, const float* __restrict__ boff,
                                            const float* __restrict__ Wattn, const float* __restrict__ battn,
                                            __hip_bfloat16* __restrict__ mapT0, __hip_bfloat16* __restrict__ mapT1,
                                            __hip_bfloat16* __restrict__ WoutT,
                                            float* __restrict__ Wall, float* __restrict__ bias64) {
    __shared__ float tile[32][33];
    int blk = blockIdx.x;
    int tx = threadIdx.x, ty = threadIdx.y;
    const float* in; __hip_bfloat16* outp; int HW, b, c0, hw0;
    if (blk < T0B) {
        int l = blk; b = l / (512 * 8); int r = l % (512 * 8);
        c0 = (r / 512) * 32; hw0 = (r % 512) * 32;
        in = map0; outp = mapT0; HW = H0c * W0c;
    } else if (blk < T0B + T1B) {
        int l = blk - T0B; b = l / (128 * 8); int r = l % (128 * 8);
        c0 = (r / 128) * 32; hw0 = (r % 128) * 32;
        in = map1; outp = mapT1; HW = H1c * W1c;
    } else if (blk < T0B + T1B + TWB) {
        int l = blk - T0B - T1B; b = 0;
        c0 = (l / 8) * 32; hw0 = (l % 8) * 32;
        in = Wout; outp = WoutT; HW = DD;
    } else {
        int l = blk - T0B - T1B - TWB;
        int tid = ty * 32 + tx;
        int idx = l * 256 + tid;               // 0..16383
        int k = idx >> 6, c = idx & 63;
        float v = (c < 4)  ? Wrd[k * 4 + c]
                : (c < 36) ? Woff[k * 32 + (c - 4)]
                : (c < 52) ? Wattn[k * 16 + (c - 36)]
                : 0.f;
        Wall[idx] = v;
        if (idx < 64) {
            float bv = (idx < 4)  ? brd[idx]
                     : (idx < 36) ? boff[idx - 4]
                     : (idx < 52) ? battn[idx - 36]
                     : 0.f;
            bias64[idx] = bv;
        }
        return;
    }
    const float* inb = in + (size_t)b * DD * HW;
    __hip_bfloat16* outb = outp + (size_t)b * DD * HW;
#pragma unroll
    for (int j = 0; j < 32; j += 8)
        tile[ty + j][tx] = inb[(size_t)(c0 + ty + j) * HW + hw0 + tx];
    __syncthreads();
#pragma unroll
    for (int j = 0; j < 32; j += 8)
        outb[(size_t)(hw0 + ty + j) * DD + c0 + tx] = __float2bfloat16(tile[tx][ty + j]);
}

// ---------------- Kernel 2: proj GEMM (fp32) + fused sampling-descriptor epilogue ----------------
__global__ __launch_bounds__(256) void proj_desc(const float* __restrict__ q,
                                                 const float* __restrict__ Wall,
                                                 const float* __restrict__ bias64,
                                                 const float* __restrict__ base_ref,
                                                 int2* __restrict__ dsi,
                                                 half4* __restrict__ dsw) {
    __shared__ float As[32][68];
    __shared__ float Bs[32][64];
    __shared__ float prs[64][68];
    int tid = threadIdx.x;
    int tx = tid & 15, ty = tid >> 4;
    int m0 = blockIdx.x * 64;
    float acc[4][4] = {};

    for (int kt = 0; kt < DD; kt += 32) {
#pragma unroll
        for (int j = 0; j < 8; j++) {
            int e = tid + 256 * j;
            int r = e >> 5, k = e & 31;
            As[k][r] = q[(size_t)(m0 + r) * DD + kt + k];
        }
#pragma unroll
        for (int j = 0; j < 8; j++) {
            int e = tid + 256 * j;
            int k = e >> 6, nn = e & 63;
            Bs[k][nn] = Wall[(size_t)(kt + k) * 64 + nn];
        }
        __syncthreads();
#pragma unroll
        for (int k = 0; k < 32; k++) {
            const float4 a4 = *(const float4*)&As[k][ty * 4];
            const float4 b4 = *(const float4*)&Bs[k][tx * 4];
            acc[0][0] += a4.x * b4.x; acc[0][1] += a4.x * b4.y; acc[0][2] += a4.x * b4.z; acc[0][3] += a4.x * b4.w;
            acc[1][0] += a4.y * b4.x; acc[1][1] += a4.y * b4.y; acc[1][2] += a4.y * b4.z; acc[1][3] += a4.y * b4.w;
            acc[2][0] += a4.z * b4.x; acc[2][1] += a4.z * b4.y; acc[2][2] += a4.z * b4.z; acc[2][3] += a4.z * b4.w;
            acc[3][0] += a4.w * b4.x; acc[3][1] += a4.w * b4.y; acc[3][2] += a4.w * b4.z; acc[3][3] += a4.w * b4.w;
        }
        __syncthreads();
    }

    float4 bias = *(const float4*)&bias64[tx * 4];
#pragma unroll
    for (int i = 0; i < 4; i++) {
        float4 v;
        v.x = acc[i][0] + bias.x;
        v.y = acc[i][1] + bias.y;
        v.z = acc[i][2] + bias.z;
        v.w = acc[i][3] + bias.w;
        *(float4*)&prs[ty * 4 + i][tx * 4] = v;
    }
    __syncthreads();

    int ql = tid >> 2, sq = tid & 3;
    int n = m0 + ql, b = n >> 13;        // QN = 8192
    const float* p = prs[ql];

    float mx = p[36];
#pragma unroll
    for (int i = 1; i < 16; i++) mx = fmaxf(mx, p[36 + i]);
    float sum = 0.f;
#pragma unroll
    for (int i = 0; i < 16; i++) sum += __expf(p[36 + i] - mx);
    float inv = 1.f / sum;

#pragma unroll
    for (int u = 0; u < 4; u++) {
        int s = sq * 4 + u;
        int l = s >> 3;
        float a = __expf(p[36 + s] - mx) * inv;

        int W = l ? W1c : W0c;
        int H = l ? H1c : H0c;
        float Wf = (float)W, Hf = (float)H;

        float bx = base_ref[(b * LL + l) * 2 + 0];
        float by = base_ref[(b * LL + l) * 2 + 1];
        bx = fminf(fmaxf(bx, EPSF), 1.f - EPSF);
        by = fminf(fmaxf(by, EPSF), 1.f - EPSF);
        float lgx = logf(bx / (1.f - bx));
        float lgy = logf(by / (1.f - by));
        float refx = 1.f / (1.f + __expf(-(lgx + p[l * 2 + 0])));
        float refy = 1.f / (1.f + __expf(-(lgy + p[l * 2 + 1])));

        float locx = refx + p[4 + s * 2 + 0] / Wf;
        float locy = refy + p[4 + s * 2 + 1] / Hf;
        if (l == 1) locy = locy - floorf(locy);   // jnp.remainder(y, 1.0)

        float gx = locx * 2.f - 1.f;
        float gy = locy * 2.f - 1.f;
        float x = ((gx + 1.f) * Wf - 1.f) * 0.5f;
        float y = ((gy + 1.f) * Hf - 1.f) * 0.5f;
        x = fminf(fmaxf(x, 0.f), Wf - 1.f);
        y = fminf(fmaxf(y, 0.f), Hf - 1.f);
        float x0f = floorf(x), y0f = floorf(y);
        float wx = x - x0f, wy = y - y0f;
        int x0 = (int)x0f, y0 = (int)y0f;
        unsigned int dx = (x0 + 1 <= W - 1) ? DD : 0;            // elems
        unsigned int dy = (y0 + 1 <= H - 1) ? (unsigned)(W * DD) : 0;
        int base = ((b * H + y0) * W + x0) * DD;

        float omx = 1.f - wx, omy = 1.f - wy;
        half4 w;
        w[0] = (_Float16)(a * omx * omy);
        w[1] = (_Float16)(a * wx  * omy);
        w[2] = (_Float16)(a * omx * wy);
        w[3] = (_Float16)(a * wx  * wy);

        dsi[(size_t)n * 16 + s] = make_int2(base, (int)((dy << 16) | dx));
        dsw[(size_t)n * 16 + s] = w;
    }
}

// ---------------- Kernel 3: sampling v4 — 8 ch/lane, 2 queries/wave, batched gathers ----------------
__global__ __launch_bounds__(256, 3) void sample_kernel(const ushort_t* __restrict__ mapT0,
                                                        const ushort_t* __restrict__ mapT1,
                                                        const int2* __restrict__ dsi,
                                                        const half4* __restrict__ dsw,
                                                        ushort_t* __restrict__ S) {
    int tid = threadIdx.x;
    int lx = tid & 63;
    int n = blockIdx.x * 8 + (tid >> 6) * 2 + (lx >> 5);   // query
    int c8 = (lx & 31) * 8;                                 // channel base
    const int2*  gi = dsi + (size_t)n * 16;
    const half4* gw = dsw + (size_t)n * 16;

    int2 g[16]; half4 wh[16];
#pragma unroll
    for (int s = 0; s < 16; s++) { g[s] = gi[s]; wh[s] = gw[s]; }

    float acc[8];
#pragma unroll
    for (int i = 0; i < 8; i++) acc[i] = 0.f;

#pragma unroll
    for (int grp = 0; grp < 4; grp++) {
        const ushort_t* mp = (grp < 2) ? mapT0 : mapT1;
        uint4 u[4][4];
#pragma unroll
        for (int j = 0; j < 4; j++) {
            int s = grp * 4 + j;
            int dx = g[s].y & 0xffff;
            int dy = (int)(((unsigned int)g[s].y) >> 16);
            const ushort_t* p0 = mp + g[s].x + c8;
            u[j][0] = *(const uint4*)(p0);
            u[j][1] = *(const uint4*)(p0 + dx);
            u[j][2] = *(const uint4*)(p0 + dy);
            u[j][3] = *(const uint4*)(p0 + dx + dy);
        }
#pragma unroll
        for (int j = 0; j < 4; j++) {
            int s = grp * 4 + j;
            float w0 = (float)wh[s][0], w1 = (float)wh[s][1], w2 = (float)wh[s][2], w3 = (float)wh[s][3];
#pragma unroll
            for (int corner = 0; corner < 4; corner++) {
                uint4 v = u[j][corner];
                float wc = (corner == 0) ? w0 : (corner == 1) ? w1 : (corner == 2) ? w2 : w3;
                acc[0] += wc * lo16f(v.x); acc[1] += wc * hi16f(v.x);
                acc[2] += wc * lo16f(v.y); acc[3] += wc * hi16f(v.y);
                acc[4] += wc * lo16f(v.z); acc[5] += wc * hi16f(v.z);
                acc[6] += wc * lo16f(v.w); acc[7] += wc * hi16f(v.w);
            }
        }
    }
    ushortx8 o;
#pragma unroll
    for (int i = 0; i < 8; i++) o[i] = f2bf(acc[i]);
    *(ushortx8*)(S + (size_t)n * DD + c8) = o;
}

// ---------------- Kernel 4: out = S(bf16) @ Wout + bout via MFMA, LDS-staged B with XOR swizzle ----------------
// grid (n-chunk 0..3, m-block 0..511); block = 4 waves, each wave 16 rows x 64 cols.
__global__ __launch_bounds__(256) void out_mfma(const ushort_t* __restrict__ S,
                                                const ushort_t* __restrict__ WT,
                                                const float* __restrict__ bout,
                                                float* __restrict__ out) {
    __shared__ ushort_t wlds[64][256];   // rows = n (chunk-local), cols = k; 16B chunks XOR-swizzled by row
    int tid = threadIdx.x;
    int n0c = blockIdx.x * 64;
    int wave = tid >> 6, lane = tid & 63;
    int m0 = blockIdx.y * 64 + wave * 16;
    int mrow = lane & 15, quad = lane >> 4;

    // stage WT rows n0c..n0c+63 (each 256 bf16 = 32 chunks of 16B), swizzle chunk ^= row&31
#pragma unroll
    for (int i = 0; i < 8; i++) {
        int idx = tid + 256 * i;          // 0..2047
        int row = idx >> 5, c = idx & 31;
        *(uint4*)&wlds[row][(c ^ (row & 31)) * 8] =
            *(const uint4*)(WT + (size_t)(n0c + row) * DD + c * 8);
    }
    __syncthreads();

    const ushort_t* Sp = S + (size_t)(m0 + mrow) * DD + quad * 8;
    short8 a[8];
#pragma unroll
    for (int k = 0; k < 8; k++) a[k] = *(const short8*)(Sp + k * 32);

    floatx4 acc[4];
#pragma unroll
    for (int nt = 0; nt < 4; nt++) acc[nt] = {0.f, 0.f, 0.f, 0.f};

#pragma unroll
    for (int nt = 0; nt < 4; nt++) {
        int row = nt * 16 + mrow;
#pragma unroll
        for (int k = 0; k < 8; k++) {
            int c = k * 4 + quad;         // chunk index 0..31
            short8 b = *(const short8*)&wlds[row][(c ^ (row & 31)) * 8];
            acc[nt] = __builtin_amdgcn_mfma_f32_16x16x32_bf16(a[k], b, acc[nt], 0, 0, 0);
        }
    }

    int rbase = quad * 4;
#pragma unroll
    for (int nt = 0; nt < 4; nt++) {
        float bv = bout[n0c + nt * 16 + mrow];
#pragma unroll
        for (int r = 0; r < 4; r++) {
            out[(size_t)(m0 + rbase + r) * DD + n0c + nt * 16 + mrow] = acc[nt][r] + bv;
        }
    }
}

// ---------------- launch ----------------
extern "C" void kernel_launch(void* const* d_in, const int* in_sizes, int n_in,
                              void* d_out, int out_size, void* d_ws, size_t ws_size,
                              hipStream_t stream) {
    const float* q        = (const float*)d_in[0];
    const float* map0     = (const float*)d_in[1];
    const float* map1     = (const float*)d_in[2];
    const float* base_ref = (const float*)d_in[3];
    const float* Wrd      = (const float*)d_in[4];
    const float* brd      = (const float*)d_in[5];
    const float* Woff     = (const float*)d_in[6];
    const float* boff     = (const float*)d_in[7];
    const float* Wattn    = (const float*)d_in[8];
    const float* battn    = (const float*)d_in[9];
    const float* Wout     = (const float*)d_in[10];
    const float* bout     = (const float*)d_in[11];
    float* out = (float*)d_out;

    // workspace layout (bytes) — total 67,305,728 (same as round 2/3, known to fit)
    char* ws = (char*)d_ws;
    __hip_bfloat16* mapT0  = (__hip_bfloat16*)(ws + 0);          // 33,554,432
    __hip_bfloat16* mapT1  = (__hip_bfloat16*)(ws + 33554432);   //  8,388,608
    __hip_bfloat16* WoutT  = (__hip_bfloat16*)(ws + 41943040);   //    131,072
    float*          Wall   = (float*)(ws + 42074112);            //     65,536
    float*          bias64 = (float*)(ws + 42139648);            //        256
    int2*           dsi    = (int2*)(ws + 42139904);             //  4,194,304
    half4*          dsw    = (half4*)(ws + 46334208);            //  4,194,304
    ushort_t*       Sbuf   = (ushort_t*)(ws + 50528512);         // 16,777,216

    // 1. all transposes + weight pack (one launch)
    prep<<<dim3(T0B + T1B + TWB + 64), dim3(32, 8), 0, stream>>>(
        map0, map1, Wout, Wrd, brd, Woff, boff, Wattn, battn,
        mapT0, mapT1, WoutT, Wall, bias64);

    // 2. projections (fp32) + sampling descriptors
    proj_desc<<<dim3(BQ * QN / 64), dim3(256), 0, stream>>>(q, Wall, bias64, base_ref, dsi, dsw);

    // 3. sampling (descriptor-driven bf16 gathers, 8 ch/lane)
    sample_kernel<<<dim3(BQ * QN / 8), dim3(256), 0, stream>>>(
        (const ushort_t*)mapT0, (const ushort_t*)mapT1, dsi, dsw, Sbuf);

    // 4. output projection (bf16 MFMA, LDS-staged B)
    out_mfma<<<dim3(4, BQ * QN / 64), dim3(256), 0, stream>>>(
        Sbuf, (const ushort_t*)WoutT, bout, out);
}